// Round 12
// baseline (298.753 us; speedup 1.0000x reference)
//
#include <hip/hip_runtime.h>

namespace {

typedef unsigned short ushort_t;
typedef short s16x8 __attribute__((ext_vector_type(8)));
typedef float f32x4 __attribute__((ext_vector_type(4)));

constexpr int B_ = 2, C_ = 64, H_ = 192, W_ = 192;
constexpr int C4 = 256;
constexpr int NPIX = H_ * W_;                       // 36864
constexpr size_t NT = (size_t)B_ * C4 * NPIX;       // 18,874,368
constexpr int PB = NPIX / 32;                       // 1152 32-pixel blocks per batch
constexpr float EPSV = 1e-20f;

constexpr int TILE = 32;
constexpr int TLH = TILE + 2;   // 34

__device__ __forceinline__ ushort_t f2bu(float x) {
    union { float f; unsigned u; } v; v.f = x;
    unsigned r = v.u + 0x7fffu + ((v.u >> 16) & 1u);   // RNE to bf16
    return (ushort_t)(r >> 16);
}
__device__ __forceinline__ float bu2f(ushort_t h) {
    union { unsigned u; float f; } v; v.u = ((unsigned)h) << 16;
    return v.f;
}

__device__ __forceinline__ void async_ld16(const ushort_t* g, ushort_t* l) {
    __builtin_amdgcn_global_load_lds(
        (const __attribute__((address_space(1))) unsigned int*)g,
        (__attribute__((address_space(3))) unsigned int*)l, 16, 0, 0);
}

// ---------------- cw -> split bf16 hi/lo + per-block cw partial sums ----------
__global__ __launch_bounds__(256) void k_prep(const float* __restrict__ cw,
                                              ushort_t* __restrict__ cwH,
                                              ushort_t* __restrict__ cwL,
                                              float* __restrict__ partial) {
    __shared__ float red[256];
    int tid = threadIdx.x;
    int i = blockIdx.x * 256 + tid;   // grid 256 -> 65536
    float w = cw[i];
    ushort_t h = f2bu(w);
    cwH[i] = h;
    cwL[i] = f2bu(w - bu2f(h));
    red[tid] = w; __syncthreads();
    for (int s2 = 128; s2 > 0; s2 >>= 1) { if (tid < s2) red[tid] += red[tid + s2]; __syncthreads(); }
    if (tid == 0) partial[blockIdx.x] = red[0];
}

// ---------------- tiny final reduction: sw sum + cw partials ----------------
__global__ __launch_bounds__(256) void k_sums2(const float* __restrict__ sw,
                                               const float* __restrict__ partial,
                                               float* __restrict__ sums) {
    __shared__ float red[256];
    int tid = threadIdx.x;
    float a = 0.f;
    for (int i = tid; i < C4 * 9; i += 256) a += sw[i];
    red[tid] = a; __syncthreads();
    for (int s2 = 128; s2 > 0; s2 >>= 1) { if (tid < s2) red[tid] += red[tid + s2]; __syncthreads(); }
    if (tid == 0) sums[0] = red[0];
    __syncthreads();
    red[tid] = partial[tid]; __syncthreads();
    for (int s2 = 128; s2 > 0; s2 >>= 1) { if (tid < s2) red[tid] += red[tid + s2]; __syncthreads(); }
    if (tid == 0) sums[1] = red[0];
}

// ---------------- fused stage 1 + stage 2 (depthwise conv) — R11 proven ------
__global__ __launch_bounds__(256) void k_stage12(
    const float* __restrict__ d, const float* __restrict__ cd,
    const float* __restrict__ s, const float* __restrict__ cs,
    const float* __restrict__ w_s_from_d, const float* __restrict__ w_prop,
    const float* __restrict__ sw, const float* __restrict__ sums,
    ushort_t* __restrict__ XP, ushort_t* __restrict__ YP)
{
    __shared__ float2 uv_[4][TLH][TLH + 1];   // 38,080 B (u=.x, v=.y)
    __shared__ float swl[4][9];

    int tid = threadIdx.x;
    int blk = blockIdx.x;
    constexpr int TX = W_ / TILE, TY = H_ / TILE;   // 6 x 6
    int tx0 = blk % TX; blk /= TX;
    int ty0 = blk % TY; blk /= TY;
    int c = blk % C_;
    int b = blk / C_;
    int h0 = ty0 * TILE, w0 = tx0 * TILE;

    const float* dbc  = d  + (size_t)(b * C_ + c) * NPIX;
    const float* cdbc = cd + (size_t)(b * C_ + c) * NPIX;

    if (tid < 36) swl[tid / 9][tid % 9] = sw[(c * 4 + tid / 9) * 9 + tid % 9];

    float w0s = w_s_from_d[0];
    float wp  = w_prop[c];
    float inv_wp1 = 1.f / (wp + 1.f);
    float inv_sw  = 1.f / (sums[0] + EPSV);
    float b1 = wp * inv_wp1;

    // fill: stage 1 on the halo-1 grid (34x34); only direction 0 survives the
    // reference's argmax over identical stacked copies.
    for (int i = tid; i < TLH * TLH; i += 256) {
        int y = i / TLH, x = i - y * TLH;
        int gh = h0 - 1 + y, gw = w0 - 1 + x;
        if ((unsigned)gh < (unsigned)H_ && (unsigned)gw < (unsigned)W_) {
            float mn = 0.f, cmn = 0.f, mx = 0.f, cmx = 0.f;
            if (gh >= 1 && gw >= 1) {
                size_t q = (size_t)(gh - 1) * W_ + (gw - 1);
                mn = dbc[q]; cmn = cdbc[q];
            }
            if (gh < H_ - 1 && gw < W_ - 1) {
                size_t q = (size_t)(gh + 1) * W_ + (gw + 1);
                mx = dbc[q]; cmx = cdbc[q];
            }
            float r = __fdividef(mn, mx + EPSV);
            r = fminf(fmaxf(r, 0.f), 1.f);
            float sfd = r * fmaf(w0s, r, 1.f - w0s);
            float cfd = cmn * cmx;
            float a1 = cfd * sfd * inv_wp1;
            float c1 = cfd * inv_wp1;
            size_t gbase = (size_t)((b * C_ + c) * 4) * NPIX + (size_t)gh * W_ + gw;
            #pragma unroll
            for (int k = 0; k < 4; ++k) {
                float s_v  = s[gbase + (size_t)k * NPIX];
                float cs_v = cs[gbase + (size_t)k * NPIX];
                float t = b1 * cs_v;
                uv_[k][y][x] = make_float2(fmaf(t, s_v, a1), t + c1);
            }
        } else {
            #pragma unroll
            for (int k = 0; k < 4; ++k) uv_[k][y][x] = make_float2(0.f, 0.f);
        }
    }
    __syncthreads();

    // conv: per-pixel, one b64 read per tap
    #pragma unroll
    for (int p = 0; p < 4; ++p) {
        int i = p * 256 + tid;
        int ty = i >> 5, tx = i & 31;
        s16x8 kx, ky;
        #pragma unroll
        for (int k = 0; k < 4; ++k) {
            float nom = 0.f, den = 0.f;
            #pragma unroll
            for (int dy = 0; dy < 3; ++dy)
                #pragma unroll
                for (int dx = 0; dx < 3; ++dx) {
                    float2 P = uv_[k][ty + dy][tx + dx];
                    float wgt = swl[k][dy * 3 + dx];
                    nom = fmaf(wgt, P.x, nom);
                    den = fmaf(wgt, P.y, den);
                }
            float xv = nom * inv_sw;
            float yv = den * inv_sw;
            ushort_t hx = f2bu(xv);
            ushort_t hy = f2bu(yv);
            kx[k]     = (short)hx;
            kx[4 + k] = (short)f2bu(xv - bu2f(hx));
            ky[k]     = (short)hy;
            ky[4 + k] = (short)f2bu(yv - bu2f(hy));
        }
        int pb = (h0 + ty) * (W_ / TILE) + (w0 >> 5);
        size_t base = ((size_t)(b * PB + pb) * 64 + c) * 256 + (size_t)tx * 8;
        *(s16x8*)(XP + base) = kx;
        *(s16x8*)(YP + base) = ky;
    }
}

// ---------------- stage 3: split-bf16 MFMA GEMM, 16-pix blocks --------------
// 256 threads (4 waves). Block tile: 128 o (grid-y half) x 16 pix.
// Wave w: o in [oh*128 + w*32, +32). Panel = 32 KB LDS -> 4 blocks/CU.
// 8 macro-stages (one per k-step, each [X 2KB | Y 2KB]); 2-barrier counted
// vmcnt schedule; A double-banked; LDS-transpose epilogue (10 KB overlaid).
__global__ __launch_bounds__(256) void k_stage3(
    const ushort_t* __restrict__ XP, const ushort_t* __restrict__ YP,
    const ushort_t* __restrict__ cwH, const ushort_t* __restrict__ cwL,
    const float* __restrict__ sums, float* __restrict__ out)
{
    __shared__ ushort_t stg[8 * 2048];   // 32 KiB

    int tid  = threadIdx.x;
    int wave = tid >> 6, lane = tid & 63;
    int l15 = lane & 15, l4 = lane >> 4;
    int pb16 = blockIdx.x;          // 0..2303
    int oh   = blockIdx.y;          // 0..1
    int b    = blockIdx.z;
    int pb32 = pb16 >> 1, ph = pb16 & 1;
    int o0 = oh * 128 + wave * 32;

    // XP element (b,pb32,g,pix32,j) at ((b*PB+pb32)*64+g)*256 + pix32*8 + j
    size_t blkbase = (size_t)(b * PB + pb32) * 16384 + (size_t)ph * 128;
    // per-thread staging source: macro j covers g in [j*8, j*8+8)
    int sel8 = tid >> 7;            // 0 = X, 1 = Y
    int gl   = (tid >> 4) & 7;
    int pl   = tid & 15;
    const ushort_t* gt = (sel8 ? YP : XP) + blkbase + (size_t)gl * 256 + (size_t)pl * 8;
    ushort_t* ldst = stg + tid * 8;  // + j*2048 per macro (matches src stride!)

    f32x4 accn[2] = {};
    f32x4 accd[2] = {};
    s16x8 rx[2], ry[2];
    s16x8 rAh[2][2], rAl[2][2];      // [bank][m]

#define MFMA __builtin_amdgcn_mfma_f32_16x16x32_bf16

#define LOADA(AB, KS) do {                                                        \
    _Pragma("unroll")                                                             \
    for (int m = 0; m < 2; ++m) {                                                 \
        size_t ro = (size_t)(o0 + m * 16 + l15) * C4 + (KS) * 32 + l4 * 8;        \
        rAh[AB][m] = *(const s16x8*)(cwH + ro);                                   \
        rAl[AB][m] = *(const s16x8*)(cwL + ro);                                   \
    } } while (0)

#define LOADB(KS) do {                                                            \
    const ushort_t* bp = stg + (KS) * 2048;                                       \
    _Pragma("unroll")                                                             \
    for (int gg = 0; gg < 2; ++gg) {                                              \
        int o_ = (l4 * 2 + gg) * 128 + l15 * 8;                                   \
        rx[gg] = *(const s16x8*)(bp + o_);                                        \
        ry[gg] = *(const s16x8*)(bp + 1024 + o_);                                 \
    } } while (0)

#define COMPUTE(AB) do {                                                          \
    s16x8 bxh = __builtin_shufflevector(rx[0], rx[1], 0,1,2,3, 8,9,10,11);        \
    s16x8 bxl = __builtin_shufflevector(rx[0], rx[1], 4,5,6,7, 12,13,14,15);      \
    s16x8 byh = __builtin_shufflevector(ry[0], ry[1], 0,1,2,3, 8,9,10,11);        \
    s16x8 byl = __builtin_shufflevector(ry[0], ry[1], 4,5,6,7, 12,13,14,15);      \
    _Pragma("unroll")                                                             \
    for (int m = 0; m < 2; ++m) {                                                 \
        accn[m] = MFMA(rAh[AB][m], bxh, accn[m], 0, 0, 0);                        \
        accn[m] = MFMA(rAh[AB][m], bxl, accn[m], 0, 0, 0);                        \
        accn[m] = MFMA(rAl[AB][m], bxh, accn[m], 0, 0, 0);                        \
        accd[m] = MFMA(rAh[AB][m], byh, accd[m], 0, 0, 0);                        \
        accd[m] = MFMA(rAh[AB][m], byl, accd[m], 0, 0, 0);                        \
        accd[m] = MFMA(rAl[AB][m], byh, accd[m], 0, 0, 0);                        \
    } } while (0)

    // prologue: 8 macro-stages (8 VMEM) + A bank 0 (4 VMEM) = 12 issued
    #pragma unroll
    for (int j = 0; j < 8; ++j)
        async_ld16(gt + (size_t)j * 2048, ldst + j * 2048);
    __builtin_amdgcn_sched_barrier(0);
    LOADA(0, 0);
    __builtin_amdgcn_sched_barrier(0);

    // macros 0-3 retired (oldest 4 of 12) -> outstanding <= 8
    asm volatile("s_waitcnt vmcnt(8)" ::: "memory");
    __builtin_amdgcn_s_barrier();
    __builtin_amdgcn_sched_barrier(0);

    LOADA(1, 1); LOADB(0); COMPUTE(0);
    LOADA(0, 2); LOADB(1); COMPUTE(1);
    LOADA(1, 3); LOADB(2); COMPUTE(0);
    LOADA(0, 4); LOADB(3); COMPUTE(1);

    // 28 issued; all 8 macros retired -> outstanding <= 20
    asm volatile("s_waitcnt vmcnt(20)" ::: "memory");
    __builtin_amdgcn_s_barrier();
    __builtin_amdgcn_sched_barrier(0);

    LOADA(1, 5); LOADB(4); COMPUTE(0);
    LOADA(0, 6); LOADB(5); COMPUTE(1);
    LOADA(1, 7); LOADB(6); COMPUTE(0);
    LOADB(7); COMPUTE(1);

#undef COMPUTE
#undef LOADB
#undef LOADA
#undef MFMA

    // -------- epilogue: LDS transpose -> full-line coalesced stores --------
    float* ts = reinterpret_cast<float*>(stg);   // 128 x 20 floats = 10,240 B
    float inv_scw = 1.f / (sums[1] + EPSV);
    __syncthreads();   // all LOADB consumers of stg finished

    #pragma unroll
    for (int pass2 = 0; pass2 < 2; ++pass2) {
        #pragma unroll
        for (int m = 0; m < 2; ++m)
            #pragma unroll
            for (int r = 0; r < 4; ++r) {
                int ol = wave * 32 + m * 16 + l4 * 4 + r;   // o-local 0..127
                float nv = accn[m][r], dv = accd[m][r];
                float val = pass2 ? dv * inv_scw : nv / (dv + EPSV);
                ts[ol * 20 + l15] = val;
            }
        __syncthreads();
        size_t gb = (pass2 ? NT : 0) + (size_t)b * C4 * NPIX
                  + (size_t)(oh * 128) * NPIX + (size_t)pb16 * 16;
        int j4 = (tid & 3) * 4;
        #pragma unroll
        for (int sp = 0; sp < 2; ++sp) {
            int ol = sp * 64 + (tid >> 2);
            f32x4 v = *(const f32x4*)&ts[ol * 20 + j4];
            *(f32x4*)&out[gb + (size_t)ol * NPIX + j4] = v;
        }
        if (pass2 == 0) __syncthreads();
    }
}

} // namespace

extern "C" void kernel_launch(void* const* d_in, const int* in_sizes, int n_in,
                              void* d_out, int out_size, void* d_ws, size_t ws_size,
                              hipStream_t stream) {
    const float* d    = (const float*)d_in[0];
    const float* cd   = (const float*)d_in[1];
    const float* s    = (const float*)d_in[2];
    const float* cs   = (const float*)d_in[3];
    const float* w_s  = (const float*)d_in[4];
    const float* wprp = (const float*)d_in[5];
    const float* cw   = (const float*)d_in[6];
    const float* sw   = (const float*)d_in[7];
    float* out = (float*)d_out;

    ushort_t* XP  = (ushort_t*)d_ws;
    ushort_t* YP  = XP + 2 * NT;
    ushort_t* cwH = YP + 2 * NT;
    ushort_t* cwL = cwH + C4 * C4;
    float* sums   = (float*)(cwL + C4 * C4);
    float* partial = sums + 2;

    k_prep<<<C4, 256, 0, stream>>>(cw, cwH, cwL, partial);
    k_sums2<<<1, 256, 0, stream>>>(sw, partial, sums);
    k_stage12<<<dim3(B_ * C_ * (H_ / TILE) * (W_ / TILE)), 256, 0, stream>>>(
        d, cd, s, cs, w_s, wprp, sw, sums, XP, YP);
    k_stage3<<<dim3(NPIX / 16, 2, B_), 256, 0, stream>>>(XP, YP, cwH, cwL, sums, out);
}

// Round 13
// 263.863 us; speedup vs baseline: 1.1322x; 1.1322x over previous
//
#include <hip/hip_runtime.h>

namespace {

typedef unsigned short ushort_t;
typedef short s16x8 __attribute__((ext_vector_type(8)));
typedef float f32x4 __attribute__((ext_vector_type(4)));

constexpr int B_ = 2, C_ = 64, H_ = 192, W_ = 192;
constexpr int C4 = 256;
constexpr int NPIX = H_ * W_;                       // 36864
constexpr size_t NT = (size_t)B_ * C4 * NPIX;       // 18,874,368
constexpr int PB = NPIX / 32;                       // 1152 32-pixel blocks per batch
constexpr float EPSV = 1e-20f;
constexpr int CHUNK = 2048;                         // ushorts per tensor per k-chunk

__device__ __forceinline__ ushort_t f2bu(float x) {
    union { float f; unsigned u; } v; v.f = x;
    unsigned r = v.u + 0x7fffu + ((v.u >> 16) & 1u);   // RNE to bf16
    return (ushort_t)(r >> 16);
}
__device__ __forceinline__ float bu2f(ushort_t h) {
    union { unsigned u; float f; } v; v.u = ((unsigned)h) << 16;
    return v.f;
}

__device__ __forceinline__ void async_ld16(const ushort_t* g, ushort_t* l) {
    __builtin_amdgcn_global_load_lds(
        (const __attribute__((address_space(1))) unsigned int*)g,
        (__attribute__((address_space(3))) unsigned int*)l, 16, 0, 0);
}

// ---------------- cw -> split bf16 hi/lo + per-block cw partial sums ----------
__global__ __launch_bounds__(256) void k_prep(const float* __restrict__ cw,
                                              ushort_t* __restrict__ cwH,
                                              ushort_t* __restrict__ cwL,
                                              float* __restrict__ partial) {
    __shared__ float red[256];
    int tid = threadIdx.x;
    int i = blockIdx.x * 256 + tid;   // grid 256 -> 65536
    float w = cw[i];
    ushort_t h = f2bu(w);
    cwH[i] = h;
    cwL[i] = f2bu(w - bu2f(h));
    red[tid] = w; __syncthreads();
    for (int s2 = 128; s2 > 0; s2 >>= 1) { if (tid < s2) red[tid] += red[tid + s2]; __syncthreads(); }
    if (tid == 0) partial[blockIdx.x] = red[0];
}

// ---------------- tiny final reduction: sw sum + cw partials ----------------
__global__ __launch_bounds__(256) void k_sums2(const float* __restrict__ sw,
                                               const float* __restrict__ partial,
                                               float* __restrict__ sums) {
    __shared__ float red[256];
    int tid = threadIdx.x;
    float a = 0.f;
    for (int i = tid; i < C4 * 9; i += 256) a += sw[i];
    red[tid] = a; __syncthreads();
    for (int s2 = 128; s2 > 0; s2 >>= 1) { if (tid < s2) red[tid] += red[tid + s2]; __syncthreads(); }
    if (tid == 0) sums[0] = red[0];
    __syncthreads();
    red[tid] = partial[tid]; __syncthreads();
    for (int s2 = 128; s2 > 0; s2 >>= 1) { if (tid < s2) red[tid] += red[tid + s2]; __syncthreads(); }
    if (tid == 0) sums[1] = red[0];
}

// ---------------- fused stage 1 + stage 2, BARRIER-FREE wave-private tiles ----
// Each wave owns a 32(w) x 8(h) output tile (halo grid 34x10) in a private LDS
// slice: no __syncthreads anywhere; same-wave ds_write->ds_read ordering comes
// from lgkmcnt (compiler-inserted via array aliasing). Conv uses 16B-aligned
// sliding-window ds_read_b128 (row stride 34 float2 = even).
// Divisions cancel: U = cs_prop*s_prop = (wp*cs*s + cfd*sfd)/(wp+1),
// X = cs_spatial*s_spatial = conv(U)/sum_sw (den/(den+1e-20) == 1).
// Emits XP/YP packed split-bf16: element (b, pb, g, pix32, j) at
// ((b*PB+pb)*64 + g)*256 + pix*8 + j ; j = [hi of k=0..3 | lo of k=0..3].
__global__ __launch_bounds__(256) void k_stage12(
    const float* __restrict__ d, const float* __restrict__ cd,
    const float* __restrict__ s, const float* __restrict__ cs,
    const float* __restrict__ w_s_from_d, const float* __restrict__ w_prop,
    const float* __restrict__ sw, const float* __restrict__ sums,
    ushort_t* __restrict__ XP, ushort_t* __restrict__ YP)
{
    __shared__ float2 uv_[4][4][10][34];   // [wave][k][y][x] = 43,520 B
    __shared__ float swl_[4][36];

    int lane = threadIdx.x & 63;
    int wave = threadIdx.x >> 6;
    int t = blockIdx.x * 4 + wave;
    int txw = t % 6;  t /= 6;      // tile col (w0 = txw*32)
    int tyw = t % 24; t /= 24;     // tile row (h0 = tyw*8)
    int c = t & 63;
    int b = t >> 6;
    int h0 = tyw * 8, w0 = txw * 32;

    const float* dbc  = d  + (size_t)(b * C_ + c) * NPIX;
    const float* cdbc = cd + (size_t)(b * C_ + c) * NPIX;

    if (lane < 36) swl_[wave][lane] = sw[(c * 4 + lane / 9) * 9 + lane % 9];

    float w0s = w_s_from_d[0];
    float wp  = w_prop[c];
    float inv_wp1 = 1.f / (wp + 1.f);
    float inv_sw  = 1.f / (sums[0] + EPSV);
    float b1 = wp * inv_wp1;

    // fill: stage 1 on the halo-1 grid (34x10); only direction 0 survives the
    // reference's argmax over identical stacked copies.
    for (int i = lane; i < 340; i += 64) {
        int y = i / 34, x = i - y * 34;
        int gh = h0 - 1 + y, gw = w0 - 1 + x;
        if ((unsigned)gh < (unsigned)H_ && (unsigned)gw < (unsigned)W_) {
            float mn = 0.f, cmn = 0.f, mx = 0.f, cmx = 0.f;
            if (gh >= 1 && gw >= 1) {
                size_t q = (size_t)(gh - 1) * W_ + (gw - 1);
                mn = dbc[q]; cmn = cdbc[q];
            }
            if (gh < H_ - 1 && gw < W_ - 1) {
                size_t q = (size_t)(gh + 1) * W_ + (gw + 1);
                mx = dbc[q]; cmx = cdbc[q];
            }
            float r = __fdividef(mn, mx + EPSV);
            r = fminf(fmaxf(r, 0.f), 1.f);
            float sfd = r * fmaf(w0s, r, 1.f - w0s);
            float cfd = cmn * cmx;
            float a1 = cfd * sfd * inv_wp1;
            float c1 = cfd * inv_wp1;
            size_t gbase = (size_t)((b * C_ + c) * 4) * NPIX + (size_t)gh * W_ + gw;
            #pragma unroll
            for (int k = 0; k < 4; ++k) {
                float s_v  = s[gbase + (size_t)k * NPIX];
                float cs_v = cs[gbase + (size_t)k * NPIX];
                float tt = b1 * cs_v;
                uv_[wave][k][y][x] = make_float2(fmaf(tt, s_v, a1), tt + c1);
            }
        } else {
            #pragma unroll
            for (int k = 0; k < 4; ++k) uv_[wave][k][y][x] = make_float2(0.f, 0.f);
        }
    }
    // NO barrier: wave-private slice; lgkmcnt orders write->read within wave.

    // conv: lane owns pixels (row r, cols col0..col0+3); sliding window via
    // three b128 reads per (k, dy) covering 6 float2 elements.
    int r = lane >> 3;
    int col0 = (lane & 7) * 4;
    s16x8 outX[4], outY[4];

    #pragma unroll
    for (int k = 0; k < 4; ++k) {
        float nom[4] = {0.f, 0.f, 0.f, 0.f};
        float den[4] = {0.f, 0.f, 0.f, 0.f};
        #pragma unroll
        for (int dy = 0; dy < 3; ++dy) {
            const f32x4* rowp = (const f32x4*)&uv_[wave][k][r + dy][col0];
            f32x4 q0 = rowp[0];   // {u0,v0,u1,v1}
            f32x4 q1 = rowp[1];   // {u2,v2,u3,v3}
            f32x4 q2 = rowp[2];   // {u4,v4,u5,v5}
            float wr[3];
            #pragma unroll
            for (int dx = 0; dx < 3; ++dx) wr[dx] = swl_[wave][k * 9 + dy * 3 + dx];
            #pragma unroll
            for (int j = 0; j < 4; ++j)
                #pragma unroll
                for (int dx = 0; dx < 3; ++dx) {
                    int e = j + dx;   // 0..5 compile-time
                    float uu = (e < 2) ? q0[e * 2] : (e < 4) ? q1[(e - 2) * 2] : q2[(e - 4) * 2];
                    float vv = (e < 2) ? q0[e * 2 + 1] : (e < 4) ? q1[(e - 2) * 2 + 1] : q2[(e - 4) * 2 + 1];
                    nom[j] = fmaf(wr[dx], uu, nom[j]);
                    den[j] = fmaf(wr[dx], vv, den[j]);
                }
        }
        #pragma unroll
        for (int j = 0; j < 4; ++j) {
            float xv = nom[j] * inv_sw;
            float yv = den[j] * inv_sw;
            ushort_t hx = f2bu(xv);
            ushort_t hy = f2bu(yv);
            outX[j][k]     = (short)hx;
            outX[j][4 + k] = (short)f2bu(xv - bu2f(hx));
            outY[j][k]     = (short)hy;
            outY[j][4 + k] = (short)f2bu(yv - bu2f(hy));
        }
    }

    // stores: 4 consecutive 16B per tensor (64B contiguous per lane)
    int pb = (h0 + r) * (W_ / 32) + txw;
    size_t base = ((size_t)(b * PB + pb) * 64 + c) * 256 + (size_t)col0 * 8;
    #pragma unroll
    for (int j = 0; j < 4; ++j) {
        *(s16x8*)(XP + base + j * 8) = outX[j];
        *(s16x8*)(YP + base + j * 8) = outY[j];
    }
}

// ---------------- stage 3: split-bf16 MFMA GEMM, monolithic LDS stage --------
// R11-proven: 512 threads (8 waves), tile 256 o x 32 pix, whole 64 KB B-panel
// staged via global_load_lds, 2-barrier counted-vmcnt schedule, LDS-transpose
// epilogue for full-line stores.
__global__ __launch_bounds__(512, 4) void k_stage3(
    const ushort_t* __restrict__ XP, const ushort_t* __restrict__ YP,
    const ushort_t* __restrict__ cwH, const ushort_t* __restrict__ cwL,
    const float* __restrict__ sums, float* __restrict__ out)
{
    __shared__ ushort_t stg[8 * 2 * CHUNK];   // 64 KiB: 8 chunks x [X 4KB | Y 4KB]

    int tid  = threadIdx.x;
    int wave = tid >> 6, lane = tid & 63;
    int l15 = lane & 15, l4 = lane >> 4;
    int pb = blockIdx.x;
    int b  = blockIdx.y;
    int o0 = wave * 32;

    size_t xbase = (size_t)(b * PB + pb) * 16384;   // ushorts: 64 g * 256
    const ushort_t* gsrc = ((wave & 4) ? YP : XP) + xbase
                         + (size_t)(wave & 3) * 512 + (size_t)lane * 8;
    ushort_t* lbase = stg + ((wave & 4) ? CHUNK : 0) + (wave & 3) * 512;

    f32x4 accn[2][2] = {};
    f32x4 accd[2][2] = {};
    s16x8 rx[2][2], ry[2][2];
    s16x8 rAh[2][2], rAl[2][2];

#define MFMA __builtin_amdgcn_mfma_f32_16x16x32_bf16

#define STAGE(KS) async_ld16(gsrc + (size_t)(KS) * 2048, lbase + (KS) * (2 * CHUNK))

#define LOADA(AB, KS) do {                                                        \
    _Pragma("unroll")                                                             \
    for (int m = 0; m < 2; ++m) {                                                 \
        size_t ro = (size_t)(o0 + m * 16 + l15) * C4 + (KS) * 32 + l4 * 8;        \
        rAh[AB][m] = *(const s16x8*)(cwH + ro);                                   \
        rAl[AB][m] = *(const s16x8*)(cwL + ro);                                   \
    } } while (0)

#define LOADB(KS) do {                                                            \
    const ushort_t* bp = stg + (KS) * (2 * CHUNK);                                \
    _Pragma("unroll")                                                             \
    for (int n = 0; n < 2; ++n)                                                   \
        _Pragma("unroll")                                                         \
        for (int gg = 0; gg < 2; ++gg) {                                          \
            int o_ = (l4 * 2 + gg) * 256 + (n * 16 + l15) * 8;                    \
            rx[n][gg] = *(const s16x8*)(bp + o_);                                 \
            ry[n][gg] = *(const s16x8*)(bp + CHUNK + o_);                         \
        } } while (0)

#define COMPUTE(AB) do {                                                          \
    _Pragma("unroll")                                                             \
    for (int n = 0; n < 2; ++n) {                                                 \
        s16x8 bxh = __builtin_shufflevector(rx[n][0], rx[n][1], 0,1,2,3, 8,9,10,11);   \
        s16x8 bxl = __builtin_shufflevector(rx[n][0], rx[n][1], 4,5,6,7, 12,13,14,15); \
        s16x8 byh = __builtin_shufflevector(ry[n][0], ry[n][1], 0,1,2,3, 8,9,10,11);   \
        s16x8 byl = __builtin_shufflevector(ry[n][0], ry[n][1], 4,5,6,7, 12,13,14,15); \
        _Pragma("unroll")                                                         \
        for (int m = 0; m < 2; ++m) {                                             \
            accn[m][n] = MFMA(rAh[AB][m], bxh, accn[m][n], 0, 0, 0);              \
            accn[m][n] = MFMA(rAh[AB][m], bxl, accn[m][n], 0, 0, 0);              \
            accn[m][n] = MFMA(rAl[AB][m], bxh, accn[m][n], 0, 0, 0);              \
            accd[m][n] = MFMA(rAh[AB][m], byh, accd[m][n], 0, 0, 0);              \
            accd[m][n] = MFMA(rAh[AB][m], byl, accd[m][n], 0, 0, 0);              \
            accd[m][n] = MFMA(rAl[AB][m], byh, accd[m][n], 0, 0, 0);              \
        } } } while (0)

    // prologue: stage ALL 8 chunks (8 VMEM), then A0 (4 VMEM)
    STAGE(0); STAGE(1); STAGE(2); STAGE(3);
    STAGE(4); STAGE(5); STAGE(6); STAGE(7);
    __builtin_amdgcn_sched_barrier(0);
    LOADA(0, 0);
    __builtin_amdgcn_sched_barrier(0);

    // wait: own S0..S3 retired (12 issued, <=8 outstanding -> >=4 retired)
    asm volatile("s_waitcnt vmcnt(8)" ::: "memory");
    __builtin_amdgcn_s_barrier();
    __builtin_amdgcn_sched_barrier(0);

    LOADA(1, 1); LOADB(0); COMPUTE(0);
    LOADA(0, 2); LOADB(1); COMPUTE(1);
    LOADA(1, 3); LOADB(2); COMPUTE(0);
    LOADA(0, 4); LOADB(3); COMPUTE(1);

    // wait: own S0..S7 retired (28 issued by now, <=20 outstanding -> >=8 retired)
    asm volatile("s_waitcnt vmcnt(20)" ::: "memory");
    __builtin_amdgcn_s_barrier();
    __builtin_amdgcn_sched_barrier(0);

    LOADA(1, 5); LOADB(4); COMPUTE(0);
    LOADA(0, 6); LOADB(5); COMPUTE(1);
    LOADA(1, 7); LOADB(6); COMPUTE(0);
    LOADB(7); COMPUTE(1);

#undef COMPUTE
#undef LOADB
#undef LOADA
#undef STAGE
#undef MFMA

    // -------- epilogue: LDS transpose -> full-line coalesced stores --------
    float* ts = reinterpret_cast<float*>(stg);   // 256 x 36 floats = 36,864 B
    float inv_scw = 1.f / (sums[1] + EPSV);
    __syncthreads();   // all LOADB consumers of stg finished

    #pragma unroll
    for (int pass2 = 0; pass2 < 2; ++pass2) {
        #pragma unroll
        for (int m = 0; m < 2; ++m)
            #pragma unroll
            for (int n = 0; n < 2; ++n)
                #pragma unroll
                for (int r = 0; r < 4; ++r) {
                    int o = o0 + m * 16 + l4 * 4 + r;
                    float nv = accn[m][n][r], dv = accd[m][n][r];
                    float val = pass2 ? dv * inv_scw : nv / (dv + EPSV);
                    ts[o * 36 + n * 16 + l15] = val;
                }
        __syncthreads();
        size_t gb = (pass2 ? NT : 0) + (size_t)b * C4 * NPIX + (size_t)pb * 32;
        int oo = tid >> 3, j = tid & 7;
        #pragma unroll
        for (int pass = 0; pass < 4; ++pass) {
            int o = pass * 64 + oo;
            f32x4 v = *(const f32x4*)&ts[o * 36 + j * 4];
            *(f32x4*)&out[gb + (size_t)o * NPIX + j * 4] = v;
        }
        if (pass2 == 0) __syncthreads();
    }
}

} // namespace

extern "C" void kernel_launch(void* const* d_in, const int* in_sizes, int n_in,
                              void* d_out, int out_size, void* d_ws, size_t ws_size,
                              hipStream_t stream) {
    const float* d    = (const float*)d_in[0];
    const float* cd   = (const float*)d_in[1];
    const float* s    = (const float*)d_in[2];
    const float* cs   = (const float*)d_in[3];
    const float* w_s  = (const float*)d_in[4];
    const float* wprp = (const float*)d_in[5];
    const float* cw   = (const float*)d_in[6];
    const float* sw   = (const float*)d_in[7];
    float* out = (float*)d_out;

    ushort_t* XP  = (ushort_t*)d_ws;
    ushort_t* YP  = XP + 2 * NT;
    ushort_t* cwH = YP + 2 * NT;
    ushort_t* cwL = cwH + C4 * C4;
    float* sums   = (float*)(cwL + C4 * C4);
    float* partial = sums + 2;

    k_prep<<<C4, 256, 0, stream>>>(cw, cwH, cwL, partial);
    k_sums2<<<1, 256, 0, stream>>>(sw, partial, sums);
    // 6 x 24 tiles per (b,c); 4 wave-tiles per block
    k_stage12<<<dim3(B_ * C_ * 144 / 4), 256, 0, stream>>>(
        d, cd, s, cs, w_s, wprp, sw, sums, XP, YP);
    k_stage3<<<dim3(PB, B_), 512, 0, stream>>>(XP, YP, cwH, cwL, sums, out);
}